// Round 9
// baseline (98.418 us; speedup 1.0000x reference)
//
#include <hip/hip_runtime.h>

// Causal attention head. B=4, T=4096, C=384, H=16. fp32 in/out.
// Round 15: R14's cooperative fusion never launched (absmax == max|ref| ->
// output stayed zero; hipLaunchCooperativeKernel + harness graph capture is
// the suspect; lesson: no grid.sync in this harness). Revert to R13 (94.8us)
// and keep the sync-free half of the plan: fuse wconv INTO qkv. Each qkv
// block converts W->WT bf16 into its own LDS (redundant; W=74KB, L2-hit),
// WTROW=392-padded so B-fragment ds_read_b128 sits at the 8-cycle structural
// floor. qkv regrided 1024x128 -> 256x512 (8 waves = 4 tile-pairs x 2-way
// K-split; 36 W elems/thread). Kills wconv kernel + 1 gap + WT global
// round-trip. QKV math bit-identical; flash_v9 byte-identical to R13.
// Fixed harness floor (256MB ws re-poison ~44us + restores) on top.

constexpr int B_DIM = 4;
constexpr int T_SEQ = 4096;
constexpr int C_DIM = 384;
constexpr int H_DIM = 16;
constexpr int NROW  = B_DIM * T_SEQ; // 16384

constexpr int WTROW = 392;           // padded k-stride (shorts) per n-row
constexpr int WTMAT = 16 * WTROW;    // 6272 shorts per matrix

typedef __bf16 bf16x8 __attribute__((ext_vector_type(8)));
typedef float  f32x4  __attribute__((ext_vector_type(4)));

__device__ __forceinline__ unsigned short f2bf(float f) {
  unsigned int u = __builtin_bit_cast(unsigned int, f);
  u += 0x7fffu + ((u >> 16) & 1u);   // RNE (finite inputs)
  return (unsigned short)(u >> 16);
}
__device__ __forceinline__ bf16x8 as_bf16x8(uint4 u) {
  return __builtin_bit_cast(bf16x8, u);
}
__device__ __forceinline__ unsigned cvt_pk_bf16(float lo, float hi) {
  unsigned r;
  asm("v_cvt_pk_bf16_f32 %0, %1, %2" : "=v"(r) : "v"(lo), "v"(hi));
  return r;
}

// ---------------------------------------------------------------------------
// Kernel 1: fused W-convert + QKV projection. grid 256 x 512 threads.
// Phase W: all 512 threads convert 18432 W elems into LDS (36 each).
// Phase QKV: 8 waves = 4 tile-pairs x 2-way K-split; tiles 4*blk..4*blk+3.
// ---------------------------------------------------------------------------
__global__ __launch_bounds__(512) void qkvw(
    const float* __restrict__ x,  const float* __restrict__ Wk,
    const float* __restrict__ Wq, const float* __restrict__ Wv,
    unsigned short* __restrict__ Kb,   // [NROW][16]
    unsigned short* __restrict__ Qb,   // [NROW][32] scaled + zero-padded
    unsigned short* __restrict__ VTb)  // [B][16][T]
{
  __shared__ __attribute__((aligned(16))) unsigned short WTl[3 * WTMAT]; // 37632B
  __shared__ float mrg[4][12 * 64];                                      // 12288B

  const int tid  = threadIdx.x;
  const int w    = tid >> 6;           // 0..7
  const int lane = tid & 63;
  const int quad = lane >> 4;
  const int col  = lane & 15;
  const int pair = w >> 1;             // 0..3: which tile of this block
  const int kw   = w & 1;              // K-split half
  const int tile = (blockIdx.x << 2) | pair;   // 0..1023
  const int r0   = tile << 4;
  const int kb   = kw * 6;

  // ---- phase W: W -> WT bf16 into LDS (layout [m][n][k], k-stride 392) ----
  {
    const float* const Ws[3] = {Wk, Wq, Wv};
#pragma unroll
    for (int e = 0; e < 36; ++e) {
      const int i = e * 512 + tid;     // 0..18431
      const int m = i / 6144;
      const int r = i - m * 6144;
      const int n = r / 384;
      const int k = r - n * 384;
      WTl[m * WTMAT + n * WTROW + k] = f2bf(Ws[m][k * 16 + n]);
    }
  }
  __syncthreads();

  // ---- phase QKV (identical math to R13's qkv_mfma) ----
  const float4* __restrict__ xp =
      reinterpret_cast<const float4*>(x + (size_t)(r0 + col) * C_DIM) + quad * 2;
  float4 araw[12];
#pragma unroll
  for (int kk = 0; kk < 6; ++kk) {
    araw[2 * kk]     = xp[(kb + kk) * 8];
    araw[2 * kk + 1] = xp[(kb + kk) * 8 + 1];
  }

  const unsigned short* const bkl = WTl + col * WTROW + quad * 8;

  f32x4 ck = {0.f, 0.f, 0.f, 0.f};
  f32x4 cq = {0.f, 0.f, 0.f, 0.f};
  f32x4 cv = {0.f, 0.f, 0.f, 0.f};
#pragma unroll
  for (int kk = 0; kk < 6; ++kk) {
    uint4 pk;
    const float4 a0 = araw[2 * kk], a1 = araw[2 * kk + 1];
    pk.x = cvt_pk_bf16(a0.x, a0.y);
    pk.y = cvt_pk_bf16(a0.z, a0.w);
    pk.z = cvt_pk_bf16(a1.x, a1.y);
    pk.w = cvt_pk_bf16(a1.z, a1.w);
    const bf16x8 av = as_bf16x8(pk);
    const int ko = (kb + kk) * 32;
    const uint4 fk = *reinterpret_cast<const uint4*>(bkl + ko);
    const uint4 fq = *reinterpret_cast<const uint4*>(bkl + WTMAT + ko);
    const uint4 fv = *reinterpret_cast<const uint4*>(bkl + 2 * WTMAT + ko);
    ck = __builtin_amdgcn_mfma_f32_16x16x32_bf16(av, as_bf16x8(fk), ck, 0, 0, 0);
    cq = __builtin_amdgcn_mfma_f32_16x16x32_bf16(av, as_bf16x8(fq), cq, 0, 0, 0);
    cv = __builtin_amdgcn_mfma_f32_16x16x32_bf16(av, as_bf16x8(fv), cv, 0, 0, 0);
  }

  if (kw == 1) {
#pragma unroll
    for (int r = 0; r < 4; ++r) {
      mrg[pair][r * 64 + lane]       = ck[r];
      mrg[pair][(4 + r) * 64 + lane] = cq[r];
      mrg[pair][(8 + r) * 64 + lane] = cv[r];
    }
  }
  __syncthreads();
  if (kw == 0) {
    const float SC = 0.25f * 1.44269504088896341f;  // softmax scale * log2(e)
#pragma unroll
    for (int r = 0; r < 4; ++r) {
      const float vk = ck[r] + mrg[pair][r * 64 + lane];
      const float vq = cq[r] + mrg[pair][(4 + r) * 64 + lane];
      const float vv = cv[r] + mrg[pair][(8 + r) * 64 + lane];
      const int row = r0 + quad * 4 + r;
      Kb[row * 16 + col]      = f2bf(vk);
      Qb[row * 32 + col]      = f2bf(vq * SC);
      Qb[row * 32 + 16 + col] = 0;
      const int bb = row >> 12, t = row & 4095;
      VTb[(((size_t)(bb * 16 + col)) << 12) + t] = f2bf(vv);
    }
  }
}

// ---------------------------------------------------------------------------
// Kernel 2: bf16 MFMA flash attention, antidiagonal-paired, reg-prefetched,
// BLOCK-LOCAL merge. grid 512: blk = p*4 + b. 8 waves; wave w walks chunks
// g = w, w+8, ... < 65 across pair (qtA=255-p, qtB=p). Partials to LDS,
// one barrier, 512-thread reduce, direct out write. (byte-identical to R13)
// ---------------------------------------------------------------------------
__global__ __launch_bounds__(512) void flash_v9(
    const unsigned short* __restrict__ Qb,
    const unsigned short* __restrict__ Kb,
    const unsigned short* __restrict__ VTb,
    float* __restrict__ out)
{
  const int tid  = threadIdx.x;
  const int w    = tid >> 6;                 // 0..7
  const int lane = tid & 63;
  const int quad = lane >> 4;
  const int col  = lane & 15;
  const int p    = blockIdx.x >> 2;          // 0..127
  const int b    = blockIdx.x & 3;
  const int qtA  = 255 - p;
  const int qtB  = p;
  const int nchA = (qtA + 4) >> 2;           // 33..64; nchA + nchB == 65

  __shared__ __attribute__((aligned(16))) unsigned short Pl[8][16 * 72]; // 18.4KB
  __shared__ float mO[8][2][256];                                        // 16KB
  __shared__ float mL[8][2][16];                                         // 1KB
  unsigned short* const P = Pl[w];

  const unsigned short* Kbase = Kb + ((size_t)(b * T_SEQ) << 4);
  const unsigned short* Vbase = VTb + (((size_t)(b * 16 + col)) << 12);
  const int poff = col * 72 + quad * 4;      // P store offset (shorts)

  f32x4 o = {0.f, 0.f, 0.f, 0.f};

  // Q fragments for both phases up front.
  const uint4* qpA = reinterpret_cast<const uint4*>(
      Qb + (((size_t)(b * T_SEQ + (qtA << 4) + col)) << 5) + quad * 8);
  const uint4* qpB = reinterpret_cast<const uint4*>(
      Qb + (((size_t)(b * T_SEQ + (qtB << 4) + col)) << 5) + quad * 8);
  const bf16x8 qaA = as_bf16x8(qpA[0]);
  const bf16x8 qaB = as_bf16x8(qpB[0]);

  auto loadK = [&](int c, uint4* k4) {
    const int kt0 = c << 2;
#pragma unroll
    for (int t = 0; t < 4; ++t)
      k4[t] = *reinterpret_cast<const uint4*>(
          Kbase + (((size_t)((kt0 + t) * 16 + col)) << 4) + quad * 8);
  };
  auto loadV = [&](int c, uint4* v2) {
    v2[0] = *reinterpret_cast<const uint4*>(Vbase + c * 64 + quad * 8);
    v2[1] = *reinterpret_cast<const uint4*>(Vbase + c * 64 + 32 + quad * 8);
  };

  auto computeP = [&](int qt, bf16x8 qa, int c, const uint4* k4, float& lref) {
    const int kt0 = c << 2;
    float lsum = 0.f;
#pragma unroll
    for (int t = 0; t < 4; ++t) {
      const int kt = kt0 + t;
      f32x4 sf;
      if (kt <= qt) {
        f32x4 z = {0.f, 0.f, 0.f, 0.f};
        // swapped: A = K tile (rows=keys), B = Q tile (cols=q). C[key][q]:
        //   q = col, key = t*16 + quad*4 + r (consecutive in r)
        sf = __builtin_amdgcn_mfma_f32_16x16x32_bf16(as_bf16x8(k4[t]), qa, z, 0, 0, 0);
        if (kt == qt) {
#pragma unroll
          for (int r = 0; r < 4; ++r)
            if (quad * 4 + r > col) sf[r] = -1e30f;   // key > q
        }
      } else {
#pragma unroll
        for (int r = 0; r < 4; ++r) sf[r] = -1e30f;
      }
      const float p0 = __builtin_amdgcn_exp2f(sf[0]);  // -1e30 -> 0
      const float p1 = __builtin_amdgcn_exp2f(sf[1]);
      const float p2 = __builtin_amdgcn_exp2f(sf[2]);
      const float p3 = __builtin_amdgcn_exp2f(sf[3]);
      lsum += (p0 + p1) + (p2 + p3);
      uint2 pr;
      pr.x = cvt_pk_bf16(p0, p1);   // RNE, same as f2bf
      pr.y = cvt_pk_bf16(p2, p3);
      *reinterpret_cast<uint2*>(P + poff + t * 16) = pr;  // ds_write_b64
    }
    lref += lsum;
  };

  // P reads typed uint2 (same as writes) -> compiler preserves
  // read-before-overwrite order vs computeP's stores into the same buffer.
  auto doPV = [&](const uint4* v2) {
    const uint2* pp = reinterpret_cast<const uint2*>(P + col * 72);
    const uint2 a0 = pp[quad * 2],     a1 = pp[quad * 2 + 1];
    const uint2 b0 = pp[8 + quad * 2], b1 = pp[8 + quad * 2 + 1];
    const uint4 p0 = {a0.x, a0.y, a1.x, a1.y};
    const uint4 p1 = {b0.x, b0.y, b1.x, b1.y};
    o = __builtin_amdgcn_mfma_f32_16x16x32_bf16(as_bf16x8(p0), as_bf16x8(v2[0]), o, 0, 0, 0);
    o = __builtin_amdgcn_mfma_f32_16x16x32_bf16(as_bf16x8(p1), as_bf16x8(v2[1]), o, 0, 0, 0);
  };

  auto writePartial = [&](int ph, float lsum) {   // to LDS merge slabs
    float l = lsum;
    l += __shfl_xor(l, 16);
    l += __shfl_xor(l, 32);
#pragma unroll
    for (int r = 0; r < 4; ++r)
      mO[w][ph][(quad * 4 + r) * 16 + col] = o[r];
    if (quad == 0) mL[w][ph][col] = l;
  };

  float lA = 0.f, lB = 0.f;
  uint4 k4[4], vcur[2], vnxt[2];

  // first chunk: g0 = w (always phase A since w < 8 < 33 <= nchA)
  int g = w;
  loadK(g, k4);
  loadV(g, vcur);
  computeP(qtA, qaA, g, k4, lA);

  int prevg = g;
  g += 8;
  while (g < 65) {
    const int c = (g < nchA) ? g : g - nchA;
    loadK(c, k4);                       // issue next chunk's K (k4 dead now)
    loadV(c, vnxt);                     // issue next chunk's V
    doPV(vcur);                         // PV of prevg (V regs arrived)
    asm volatile("" ::: "memory");      // P reads stay above P overwrites
    if (prevg < nchA && g >= nchA) {    // phase boundary: flush A partial
      writePartial(0, lA);
      o = (f32x4){0.f, 0.f, 0.f, 0.f};
    }
    if (g < nchA) computeP(qtA, qaA, c, k4, lA);
    else          computeP(qtB, qaB, c, k4, lB);
    vcur[0] = vnxt[0];
    vcur[1] = vnxt[1];
    prevg = g;
    g += 8;
  }
  doPV(vcur);                           // PV of the last chunk
  if (prevg < nchA) {                   // wave never reached phase B
    writePartial(0, lA);
    o = (f32x4){0.f, 0.f, 0.f, 0.f};
    writePartial(1, 0.f);               // zero partial for B
  } else {
    writePartial(1, lB);
  }

  __syncthreads();

  // ---- block-local merge: 512 threads, tid>>8 = phase, tid&255 = elem ----
  {
    const int ph = tid >> 8;            // 0 -> qtA, 1 -> qtB
    const int i  = tid & 255;           // (row<<4)|col within the 16x16 tile
    float O = 0.f, L = 0.f;
#pragma unroll
    for (int ww = 0; ww < 8; ++ww) {
      O += mO[ww][ph][i];
      L += mL[ww][ph][i >> 4];
    }
    const int qt = ph ? qtB : qtA;
    out[(size_t)(b * T_SEQ + (qt << 4)) * 16 + i] = O / L;
  }
}

extern "C" void kernel_launch(void* const* d_in, const int* in_sizes, int n_in,
                              void* d_out, int out_size, void* d_ws, size_t ws_size,
                              hipStream_t stream) {
  const float* x  = (const float*)d_in[0];
  const float* Wk = (const float*)d_in[1];
  const float* Wq = (const float*)d_in[2];
  const float* Wv = (const float*)d_in[3];
  float* outp = (float*)d_out;

  // ws: Qb [NROW*32]sh | Kb [NROW*16]sh | 64 slack | VTb [NROW*16]sh (~2 MB)
  unsigned short* Qb  = (unsigned short*)d_ws;
  unsigned short* Kb  = Qb + (size_t)NROW * 32;
  unsigned short* VTb = Kb + (size_t)NROW * 16 + 64;

  qkvw<<<256, 512, 0, stream>>>(x, Wk, Wq, Wv, Kb, Qb, VTb);
  flash_v9<<<512, 512, 0, stream>>>(Qb, Kb, VTb, outp);
}

// Round 10
// 89.233 us; speedup vs baseline: 1.1029x; 1.1029x over previous
//
#include <hip/hip_runtime.h>

// Causal attention head. B=4, T=4096, C=384, H=16. fp32 in/out.
// Round 16: fix R15's phase-W coalescing bug. R15 (98.4) regressed vs R13
// (94.8) because each block's W->LDS conversion read W[k*16+n] with
// consecutive threads stepping k -> stride-64B scalar loads, 64 lines/wave
// instruction, ~6-7us device-wide. Fix: thread loads float4 of 4 consecutive
// W elements (4 n's, same k; perfectly coalesced 16B/lane), scatters 4 bf16
// into the LDS transpose WTl[n][k] (banks differ by 4 -> <=2-way, free).
// 9 float4/thread. Everything else byte-identical to R15 (qkv math, padded
// WTROW=392 B-fragment reads, flash_v9 with block-local merge).
// Fixed harness floor (256MB ws re-poison ~44us + restores) on top.

constexpr int B_DIM = 4;
constexpr int T_SEQ = 4096;
constexpr int C_DIM = 384;
constexpr int H_DIM = 16;
constexpr int NROW  = B_DIM * T_SEQ; // 16384

constexpr int WTROW = 392;           // padded k-stride (shorts) per n-row
constexpr int WTMAT = 16 * WTROW;    // 6272 shorts per matrix

typedef __bf16 bf16x8 __attribute__((ext_vector_type(8)));
typedef float  f32x4  __attribute__((ext_vector_type(4)));

__device__ __forceinline__ unsigned short f2bf(float f) {
  unsigned int u = __builtin_bit_cast(unsigned int, f);
  u += 0x7fffu + ((u >> 16) & 1u);   // RNE (finite inputs)
  return (unsigned short)(u >> 16);
}
__device__ __forceinline__ bf16x8 as_bf16x8(uint4 u) {
  return __builtin_bit_cast(bf16x8, u);
}
__device__ __forceinline__ unsigned cvt_pk_bf16(float lo, float hi) {
  unsigned r;
  asm("v_cvt_pk_bf16_f32 %0, %1, %2" : "=v"(r) : "v"(lo), "v"(hi));
  return r;
}

// ---------------------------------------------------------------------------
// Kernel 1: fused W-convert + QKV projection. grid 256 x 512 threads.
// Phase W: coalesced float4 loads of W, bf16 transpose-scatter into LDS.
// Phase QKV: 8 waves = 4 tile-pairs x 2-way K-split; tiles 4*blk..4*blk+3.
// ---------------------------------------------------------------------------
__global__ __launch_bounds__(512) void qkvw(
    const float* __restrict__ x,  const float* __restrict__ Wk,
    const float* __restrict__ Wq, const float* __restrict__ Wv,
    unsigned short* __restrict__ Kb,   // [NROW][16]
    unsigned short* __restrict__ Qb,   // [NROW][32] scaled + zero-padded
    unsigned short* __restrict__ VTb)  // [B][16][T]
{
  __shared__ __attribute__((aligned(16))) unsigned short WTl[3 * WTMAT]; // 37632B
  __shared__ float mrg[4][12 * 64];                                      // 12288B

  const int tid  = threadIdx.x;
  const int w    = tid >> 6;           // 0..7
  const int lane = tid & 63;
  const int quad = lane >> 4;
  const int col  = lane & 15;
  const int pair = w >> 1;             // 0..3: which tile of this block
  const int kw   = w & 1;              // K-split half
  const int tile = (blockIdx.x << 2) | pair;   // 0..1023
  const int r0   = tile << 4;
  const int kb   = kw * 6;

  // ---- phase W: W[k][n] -> WTl[m][n][k] bf16 (k-stride 392) ----
  // thread: float4 = 4 consecutive W elems (same k, n..n+3) -- coalesced.
  {
    const float* const Ws[3] = {Wk, Wq, Wv};
#pragma unroll
    for (int e = 0; e < 9; ++e) {
      const int i4 = e * 512 + tid;          // 0..4607 (4608 float4s total)
      const int m  = i4 / 1536;
      const int j4 = (i4 - m * 1536) * 4;    // elem index in matrix, %4==0
      const int k  = j4 >> 4;
      const int n  = j4 & 15;                // 0,4,8,12
      const float4 v = *reinterpret_cast<const float4*>(Ws[m] + j4);
      unsigned short* const dst = WTl + m * WTMAT + k;
      dst[(n + 0) * WTROW] = f2bf(v.x);
      dst[(n + 1) * WTROW] = f2bf(v.y);
      dst[(n + 2) * WTROW] = f2bf(v.z);
      dst[(n + 3) * WTROW] = f2bf(v.w);
    }
  }
  __syncthreads();

  // ---- phase QKV (identical math to R13's qkv_mfma) ----
  const float4* __restrict__ xp =
      reinterpret_cast<const float4*>(x + (size_t)(r0 + col) * C_DIM) + quad * 2;
  float4 araw[12];
#pragma unroll
  for (int kk = 0; kk < 6; ++kk) {
    araw[2 * kk]     = xp[(kb + kk) * 8];
    araw[2 * kk + 1] = xp[(kb + kk) * 8 + 1];
  }

  const unsigned short* const bkl = WTl + col * WTROW + quad * 8;

  f32x4 ck = {0.f, 0.f, 0.f, 0.f};
  f32x4 cq = {0.f, 0.f, 0.f, 0.f};
  f32x4 cv = {0.f, 0.f, 0.f, 0.f};
#pragma unroll
  for (int kk = 0; kk < 6; ++kk) {
    uint4 pk;
    const float4 a0 = araw[2 * kk], a1 = araw[2 * kk + 1];
    pk.x = cvt_pk_bf16(a0.x, a0.y);
    pk.y = cvt_pk_bf16(a0.z, a0.w);
    pk.z = cvt_pk_bf16(a1.x, a1.y);
    pk.w = cvt_pk_bf16(a1.z, a1.w);
    const bf16x8 av = as_bf16x8(pk);
    const int ko = (kb + kk) * 32;
    const uint4 fk = *reinterpret_cast<const uint4*>(bkl + ko);
    const uint4 fq = *reinterpret_cast<const uint4*>(bkl + WTMAT + ko);
    const uint4 fv = *reinterpret_cast<const uint4*>(bkl + 2 * WTMAT + ko);
    ck = __builtin_amdgcn_mfma_f32_16x16x32_bf16(av, as_bf16x8(fk), ck, 0, 0, 0);
    cq = __builtin_amdgcn_mfma_f32_16x16x32_bf16(av, as_bf16x8(fq), cq, 0, 0, 0);
    cv = __builtin_amdgcn_mfma_f32_16x16x32_bf16(av, as_bf16x8(fv), cv, 0, 0, 0);
  }

  if (kw == 1) {
#pragma unroll
    for (int r = 0; r < 4; ++r) {
      mrg[pair][r * 64 + lane]       = ck[r];
      mrg[pair][(4 + r) * 64 + lane] = cq[r];
      mrg[pair][(8 + r) * 64 + lane] = cv[r];
    }
  }
  __syncthreads();
  if (kw == 0) {
    const float SC = 0.25f * 1.44269504088896341f;  // softmax scale * log2(e)
#pragma unroll
    for (int r = 0; r < 4; ++r) {
      const float vk = ck[r] + mrg[pair][r * 64 + lane];
      const float vq = cq[r] + mrg[pair][(4 + r) * 64 + lane];
      const float vv = cv[r] + mrg[pair][(8 + r) * 64 + lane];
      const int row = r0 + quad * 4 + r;
      Kb[row * 16 + col]      = f2bf(vk);
      Qb[row * 32 + col]      = f2bf(vq * SC);
      Qb[row * 32 + 16 + col] = 0;
      const int bb = row >> 12, t = row & 4095;
      VTb[(((size_t)(bb * 16 + col)) << 12) + t] = f2bf(vv);
    }
  }
}

// ---------------------------------------------------------------------------
// Kernel 2: bf16 MFMA flash attention, antidiagonal-paired, reg-prefetched,
// BLOCK-LOCAL merge. grid 512: blk = p*4 + b. 8 waves; wave w walks chunks
// g = w, w+8, ... < 65 across pair (qtA=255-p, qtB=p). Partials to LDS,
// one barrier, 512-thread reduce, direct out write. (byte-identical to R13)
// ---------------------------------------------------------------------------
__global__ __launch_bounds__(512) void flash_v9(
    const unsigned short* __restrict__ Qb,
    const unsigned short* __restrict__ Kb,
    const unsigned short* __restrict__ VTb,
    float* __restrict__ out)
{
  const int tid  = threadIdx.x;
  const int w    = tid >> 6;                 // 0..7
  const int lane = tid & 63;
  const int quad = lane >> 4;
  const int col  = lane & 15;
  const int p    = blockIdx.x >> 2;          // 0..127
  const int b    = blockIdx.x & 3;
  const int qtA  = 255 - p;
  const int qtB  = p;
  const int nchA = (qtA + 4) >> 2;           // 33..64; nchA + nchB == 65

  __shared__ __attribute__((aligned(16))) unsigned short Pl[8][16 * 72]; // 18.4KB
  __shared__ float mO[8][2][256];                                        // 16KB
  __shared__ float mL[8][2][16];                                         // 1KB
  unsigned short* const P = Pl[w];

  const unsigned short* Kbase = Kb + ((size_t)(b * T_SEQ) << 4);
  const unsigned short* Vbase = VTb + (((size_t)(b * 16 + col)) << 12);
  const int poff = col * 72 + quad * 4;      // P store offset (shorts)

  f32x4 o = {0.f, 0.f, 0.f, 0.f};

  // Q fragments for both phases up front.
  const uint4* qpA = reinterpret_cast<const uint4*>(
      Qb + (((size_t)(b * T_SEQ + (qtA << 4) + col)) << 5) + quad * 8);
  const uint4* qpB = reinterpret_cast<const uint4*>(
      Qb + (((size_t)(b * T_SEQ + (qtB << 4) + col)) << 5) + quad * 8);
  const bf16x8 qaA = as_bf16x8(qpA[0]);
  const bf16x8 qaB = as_bf16x8(qpB[0]);

  auto loadK = [&](int c, uint4* k4) {
    const int kt0 = c << 2;
#pragma unroll
    for (int t = 0; t < 4; ++t)
      k4[t] = *reinterpret_cast<const uint4*>(
          Kbase + (((size_t)((kt0 + t) * 16 + col)) << 4) + quad * 8);
  };
  auto loadV = [&](int c, uint4* v2) {
    v2[0] = *reinterpret_cast<const uint4*>(Vbase + c * 64 + quad * 8);
    v2[1] = *reinterpret_cast<const uint4*>(Vbase + c * 64 + 32 + quad * 8);
  };

  auto computeP = [&](int qt, bf16x8 qa, int c, const uint4* k4, float& lref) {
    const int kt0 = c << 2;
    float lsum = 0.f;
#pragma unroll
    for (int t = 0; t < 4; ++t) {
      const int kt = kt0 + t;
      f32x4 sf;
      if (kt <= qt) {
        f32x4 z = {0.f, 0.f, 0.f, 0.f};
        // swapped: A = K tile (rows=keys), B = Q tile (cols=q). C[key][q]:
        //   q = col, key = t*16 + quad*4 + r (consecutive in r)
        sf = __builtin_amdgcn_mfma_f32_16x16x32_bf16(as_bf16x8(k4[t]), qa, z, 0, 0, 0);
        if (kt == qt) {
#pragma unroll
          for (int r = 0; r < 4; ++r)
            if (quad * 4 + r > col) sf[r] = -1e30f;   // key > q
        }
      } else {
#pragma unroll
        for (int r = 0; r < 4; ++r) sf[r] = -1e30f;
      }
      const float p0 = __builtin_amdgcn_exp2f(sf[0]);  // -1e30 -> 0
      const float p1 = __builtin_amdgcn_exp2f(sf[1]);
      const float p2 = __builtin_amdgcn_exp2f(sf[2]);
      const float p3 = __builtin_amdgcn_exp2f(sf[3]);
      lsum += (p0 + p1) + (p2 + p3);
      uint2 pr;
      pr.x = cvt_pk_bf16(p0, p1);   // RNE, same as f2bf
      pr.y = cvt_pk_bf16(p2, p3);
      *reinterpret_cast<uint2*>(P + poff + t * 16) = pr;  // ds_write_b64
    }
    lref += lsum;
  };

  // P reads typed uint2 (same as writes) -> compiler preserves
  // read-before-overwrite order vs computeP's stores into the same buffer.
  auto doPV = [&](const uint4* v2) {
    const uint2* pp = reinterpret_cast<const uint2*>(P + col * 72);
    const uint2 a0 = pp[quad * 2],     a1 = pp[quad * 2 + 1];
    const uint2 b0 = pp[8 + quad * 2], b1 = pp[8 + quad * 2 + 1];
    const uint4 p0 = {a0.x, a0.y, a1.x, a1.y};
    const uint4 p1 = {b0.x, b0.y, b1.x, b1.y};
    o = __builtin_amdgcn_mfma_f32_16x16x32_bf16(as_bf16x8(p0), as_bf16x8(v2[0]), o, 0, 0, 0);
    o = __builtin_amdgcn_mfma_f32_16x16x32_bf16(as_bf16x8(p1), as_bf16x8(v2[1]), o, 0, 0, 0);
  };

  auto writePartial = [&](int ph, float lsum) {   // to LDS merge slabs
    float l = lsum;
    l += __shfl_xor(l, 16);
    l += __shfl_xor(l, 32);
#pragma unroll
    for (int r = 0; r < 4; ++r)
      mO[w][ph][(quad * 4 + r) * 16 + col] = o[r];
    if (quad == 0) mL[w][ph][col] = l;
  };

  float lA = 0.f, lB = 0.f;
  uint4 k4[4], vcur[2], vnxt[2];

  // first chunk: g0 = w (always phase A since w < 8 < 33 <= nchA)
  int g = w;
  loadK(g, k4);
  loadV(g, vcur);
  computeP(qtA, qaA, g, k4, lA);

  int prevg = g;
  g += 8;
  while (g < 65) {
    const int c = (g < nchA) ? g : g - nchA;
    loadK(c, k4);                       // issue next chunk's K (k4 dead now)
    loadV(c, vnxt);                     // issue next chunk's V
    doPV(vcur);                         // PV of prevg (V regs arrived)
    asm volatile("" ::: "memory");      // P reads stay above P overwrites
    if (prevg < nchA && g >= nchA) {    // phase boundary: flush A partial
      writePartial(0, lA);
      o = (f32x4){0.f, 0.f, 0.f, 0.f};
    }
    if (g < nchA) computeP(qtA, qaA, c, k4, lA);
    else          computeP(qtB, qaB, c, k4, lB);
    vcur[0] = vnxt[0];
    vcur[1] = vnxt[1];
    prevg = g;
    g += 8;
  }
  doPV(vcur);                           // PV of the last chunk
  if (prevg < nchA) {                   // wave never reached phase B
    writePartial(0, lA);
    o = (f32x4){0.f, 0.f, 0.f, 0.f};
    writePartial(1, 0.f);               // zero partial for B
  } else {
    writePartial(1, lB);
  }

  __syncthreads();

  // ---- block-local merge: 512 threads, tid>>8 = phase, tid&255 = elem ----
  {
    const int ph = tid >> 8;            // 0 -> qtA, 1 -> qtB
    const int i  = tid & 255;           // (row<<4)|col within the 16x16 tile
    float O = 0.f, L = 0.f;
#pragma unroll
    for (int ww = 0; ww < 8; ++ww) {
      O += mO[ww][ph][i];
      L += mL[ww][ph][i >> 4];
    }
    const int qt = ph ? qtB : qtA;
    out[(size_t)(b * T_SEQ + (qt << 4)) * 16 + i] = O / L;
  }
}

extern "C" void kernel_launch(void* const* d_in, const int* in_sizes, int n_in,
                              void* d_out, int out_size, void* d_ws, size_t ws_size,
                              hipStream_t stream) {
  const float* x  = (const float*)d_in[0];
  const float* Wk = (const float*)d_in[1];
  const float* Wq = (const float*)d_in[2];
  const float* Wv = (const float*)d_in[3];
  float* outp = (float*)d_out;

  // ws: Qb [NROW*32]sh | Kb [NROW*16]sh | 64 slack | VTb [NROW*16]sh (~2 MB)
  unsigned short* Qb  = (unsigned short*)d_ws;
  unsigned short* Kb  = Qb + (size_t)NROW * 32;
  unsigned short* VTb = Kb + (size_t)NROW * 16 + 64;

  qkvw<<<256, 512, 0, stream>>>(x, Wk, Wq, Wv, Kb, Qb, VTb);
  flash_v9<<<512, 512, 0, stream>>>(Qb, Kb, VTb, outp);
}